// Round 2
// baseline (435.408 us; speedup 1.0000x reference)
//
#include <hip/hip_runtime.h>

#define M_DIM 4096
#define K_DIM 16384
#define N_DIM 256
#define SPLIT 16

typedef __bf16 bf16x8 __attribute__((ext_vector_type(8)));
typedef __bf16 bf16x4 __attribute__((ext_vector_type(4)));
typedef float f32x4 __attribute__((ext_vector_type(4)));
typedef unsigned short us4 __attribute__((ext_vector_type(4)));

__device__ __forceinline__ unsigned short f2bf(float f) {
  unsigned int u = __float_as_uint(f);
  u += 0x7fffu + ((u >> 16) & 1u);
  return (unsigned short)(u >> 16);
}

// ---------------- W transpose + convert: Wt[n][k] = bf16(W[k][n]) ----------------
__global__ __launch_bounds__(256) void wt_kernel(const float* __restrict__ W,
                                                 __bf16* __restrict__ Wt) {
  __shared__ float tile[64][65];
  const int k0 = blockIdx.x * 64, n0 = blockIdx.y * 64;
  const int t = threadIdx.x;
#pragma unroll
  for (int r = 0; r < 4; ++r) {
    int idx4 = r * 256 + t;
    int kr = idx4 >> 4, c4 = idx4 & 15;
    f32x4 v = *(const f32x4*)(W + (size_t)(k0 + kr) * N_DIM + n0 + c4 * 4);
#pragma unroll
    for (int j = 0; j < 4; ++j) tile[kr][c4 * 4 + j] = v[j];
  }
  __syncthreads();
#pragma unroll
  for (int r = 0; r < 4; ++r) {
    int nr = (t >> 4) + r * 16, k4 = t & 15;  // lanes walk k -> coalesced store
    bf16x4 o;
#pragma unroll
    for (int j = 0; j < 4; ++j) o[j] = (__bf16)tile[k4 * 4 + j][nr];
    *(bf16x4*)(Wt + (size_t)(n0 + nr) * K_DIM + k0 + k4 * 4) = o;
  }
}

// ---------------- Main MFMA GEMM ----------------
// BM=64, BN=256 (full O -> x fetched exactly once), BK=64, 256 threads = 4 waves.
// Wave w owns the 64x64 subtile at n = w*64: 4x4 tiles of mfma_f32_16x16x32_bf16.
// LDS = 9216 (As, stride 72: b128 frag reads 2-way = free) + 32768 (Bs) = 41 KiB
// -> 3 blocks/CU; grid 64x16 = 1024 blocks oversubscribes for cross-block overlap.
__global__ __launch_bounds__(256, 3) void gemm_kernel(const float* __restrict__ x,
                                                      const __bf16* __restrict__ Wt,
                                                      __bf16* __restrict__ part,
                                                      int kslice) {
  __shared__ __bf16 As[64 * 72];
  // Bs: 8-row interleaved DMA layout (no pad allowed for global_load_lds):
  //   elem(n,k) at idx = (n>>3)*512 + (k>>3)*64 + (n&7)*8 + (k&7)
  __shared__ __bf16 Bs[256 * 64];

  const int t = threadIdx.x;
  const int l = t & 63;
  const int w = t >> 6;  // wave id == n-block
  const int la = l & 15, q = l >> 4;
  const int m0 = blockIdx.x * 64;
  const int kbase = blockIdx.y * kslice;

  f32x4 acc[4][4];
  const f32x4 zero = {0.f, 0.f, 0.f, 0.f};
#pragma unroll
  for (int i = 0; i < 4; ++i)
#pragma unroll
    for (int j = 0; j < 4; ++j) acc[i][j] = zero;

  const int niter = kslice >> 6;
  for (int it = 0; it < niter; ++it) {
    const int k0 = kbase + it * 64;

    // ---- stage B first (DMA in flight while A converts): 8 global_load_lds/wave ----
#pragma unroll
    for (int c = 0; c < 8; ++c) {
      int nb = w * 64 + c * 8;  // 8 n-rows x 64 k = 1024 B contiguous LDS per instr
      const __bf16* g = Wt + (size_t)(nb + (l & 7)) * K_DIM + k0 + ((l >> 3) * 8);
      __bf16* lp = &Bs[nb * 64];  // wave-uniform LDS base
      __builtin_amdgcn_global_load_lds((const __attribute__((address_space(1))) void*)g,
                                       (__attribute__((address_space(3))) void*)lp, 16, 0, 0);
    }

    // ---- stage A: fp32 float4 loads -> native bf16 cvt -> b64 LDS writes ----
#pragma unroll
    for (int r = 0; r < 4; ++r) {
      int idx4 = r * 256 + t;
      int row = idx4 >> 4, c4 = idx4 & 15;
      f32x4 v = *(const f32x4*)(x + (size_t)(m0 + row) * K_DIM + k0 + c4 * 4);
      bf16x4 o = {(__bf16)v[0], (__bf16)v[1], (__bf16)v[2], (__bf16)v[3]};
      *(bf16x4*)(&As[row * 72 + c4 * 4]) = o;
    }
    __syncthreads();

    // ---- fragments + 32 MFMAs per wave ----
#pragma unroll
    for (int ks = 0; ks < 2; ++ks) {
      const int kb = ks * 32 + q * 8;
      bf16x8 a[4], b[4];
#pragma unroll
      for (int i = 0; i < 4; ++i)
        a[i] = *(const bf16x8*)(&As[(i * 16 + la) * 72 + kb]);
#pragma unroll
      for (int j = 0; j < 4; ++j) {
        int n = w * 64 + j * 16 + la;
        b[j] = *(const bf16x8*)(&Bs[(n >> 3) * 512 + (kb >> 3) * 64 + (n & 7) * 8]);
      }
#pragma unroll
      for (int i = 0; i < 4; ++i)
#pragma unroll
        for (int j = 0; j < 4; ++j)
          acc[i][j] = __builtin_amdgcn_mfma_f32_16x16x32_bf16(a[i], b[j], acc[i][j], 0, 0, 0);
    }
    __syncthreads();
  }

  // ---- epilogue: bf16 partials (C/D layout: col=lane&15, row=quad*4+reg) ----
  __bf16* pbase = part + (size_t)blockIdx.y * ((size_t)M_DIM * N_DIM);
#pragma unroll
  for (int i = 0; i < 4; ++i) {
    int r0 = m0 + i * 16 + q * 4;
#pragma unroll
    for (int j = 0; j < 4; ++j) {
      int c = w * 64 + j * 16 + la;
#pragma unroll
      for (int r = 0; r < 4; ++r)
        pbase[(size_t)(r0 + r) * N_DIM + c] = (__bf16)acc[i][j][r];
    }
  }
}

// ---------------- reduce partials + exact fp32 bit-flip correction + bias ----------------
__global__ __launch_bounds__(256) void reduce_kernel(const __bf16* __restrict__ part,
                                                     const float* __restrict__ x,
                                                     const float* __restrict__ W,
                                                     const float* __restrict__ bvec,
                                                     const float* __restrict__ coeffp,
                                                     const int* __restrict__ idx,
                                                     const int* __restrict__ bp,
                                                     float* __restrict__ out) {
  const int row = blockIdx.x;
  const int o = threadIdx.x;
  const int iv = idx[row];
  const float g = x[(size_t)row * K_DIM + iv];
  const int bits = __float_as_int(g) ^ (1 << bp[row]);
  const float upd = __int_as_float(bits) - g;  // swap_sim(g) - g, exact fp32
  const float coeff = coeffp[0];
  const size_t off = (size_t)row * N_DIM + o;
  float sum = 0.f;
#pragma unroll
  for (int s = 0; s < SPLIT; ++s)
    sum += (float)part[(size_t)s * ((size_t)M_DIM * N_DIM) + off];
  out[off] = sum + coeff * upd * W[(size_t)iv * N_DIM + o] + bvec[o];
}

extern "C" void kernel_launch(void* const* d_in, const int* in_sizes, int n_in,
                              void* d_out, int out_size, void* d_ws, size_t ws_size,
                              hipStream_t stream) {
  const float* x = (const float*)d_in[0];
  const float* W = (const float*)d_in[1];
  const float* b = (const float*)d_in[2];
  const float* coeff = (const float*)d_in[3];
  const int* idx = (const int*)d_in[4];
  const int* bp = (const int*)d_in[5];
  float* out = (float*)d_out;

  __bf16* Wt = (__bf16*)d_ws;
  const size_t wt_bytes = (size_t)K_DIM * N_DIM * 2;  // 8 MiB
  __bf16* part = (__bf16*)((char*)d_ws + wt_bytes);   // 16 x 2 MiB partials

  hipLaunchKernelGGL(wt_kernel, dim3(K_DIM / 64, N_DIM / 64), dim3(256), 0, stream, W, Wt);
  hipLaunchKernelGGL(gemm_kernel, dim3(M_DIM / 64, SPLIT), dim3(256), 0, stream,
                     x, Wt, part, K_DIM / SPLIT);
  hipLaunchKernelGGL(reduce_kernel, dim3(M_DIM), dim3(256), 0, stream,
                     part, x, W, b, coeff, idx, bp, out);
}

// Round 3
// 413.696 us; speedup vs baseline: 1.0525x; 1.0525x over previous
//
#include <hip/hip_runtime.h>

#define M_DIM 4096
#define K_DIM 16384
#define N_DIM 256
#define SPLIT 8
#define BK 64
#define KSLICE (K_DIM / SPLIT)
#define NITER (KSLICE / BK)  // 32

typedef __bf16 bf16x8 __attribute__((ext_vector_type(8)));
typedef __bf16 bf16x4 __attribute__((ext_vector_type(4)));
typedef float f32x4 __attribute__((ext_vector_type(4)));

// ---------------- W transpose + convert: Wt[n][k] = bf16(W[k][n]) ----------------
__global__ __launch_bounds__(256) void wt_kernel(const float* __restrict__ W,
                                                 __bf16* __restrict__ Wt) {
  __shared__ float tile[64][65];
  const int k0 = blockIdx.x * 64, n0 = blockIdx.y * 64;
  const int t = threadIdx.x;
#pragma unroll
  for (int r = 0; r < 4; ++r) {
    int idx4 = r * 256 + t;
    int kr = idx4 >> 4, c4 = idx4 & 15;
    f32x4 v = *(const f32x4*)(W + (size_t)(k0 + kr) * N_DIM + n0 + c4 * 4);
#pragma unroll
    for (int j = 0; j < 4; ++j) tile[kr][c4 * 4 + j] = v[j];
  }
  __syncthreads();
#pragma unroll
  for (int r = 0; r < 4; ++r) {
    int nr = (t >> 4) + r * 16, k4 = t & 15;
    bf16x4 o;
#pragma unroll
    for (int j = 0; j < 4; ++j) o[j] = (__bf16)tile[k4 * 4 + j][nr];
    *(bf16x4*)(Wt + (size_t)(n0 + nr) * K_DIM + k0 + k4 * 4) = o;
  }
}

// ---------------- Main MFMA GEMM: global->reg->LDS software pipeline ----------------
// BM=64, BN=256, BK=64, 256 thr = 4 waves; wave w owns 64m x 64n at n=w*64
// (4x4 tiles of mfma_f32_16x16x32_bf16). Loads for iter k+1 are issued after the
// LDS-ready barrier of iter k and complete under the MFMA phase (AITER-style:
// the vmcnt wait lands at iter k+1's ds_write, not at a barrier drain).
// LDS = As 64x72 (9 KiB) + Bs 256x72 (36 KiB) = 45 KiB -> 3 blocks/CU.
__global__ __launch_bounds__(256, 3) void gemm_kernel(const float* __restrict__ x,
                                                      const __bf16* __restrict__ Wt,
                                                      __bf16* __restrict__ part) {
  __shared__ __bf16 As[64 * 72];
  __shared__ __bf16 Bs[256 * 72];

  const int t = threadIdx.x;
  const int l = t & 63;
  const int w = t >> 6;
  const int la = l & 15, q = l >> 4;
  const int m0 = blockIdx.x * 64;
  const int kbase = blockIdx.y * KSLICE;

  // A staging: 4 float4/thread covering 64 rows x 64 k
  const int arow = t >> 4, ac4 = t & 15;
  // B staging: 8 x 16B/thread covering 256 rows x 64 k (8 lanes per 128B row seg)
  const int bn = t >> 3, bk8 = (t & 7) * 8;

  const float* ap = x + (size_t)(m0 + arow) * K_DIM + kbase + ac4 * 4;
  const __bf16* bp = Wt + (size_t)bn * K_DIM + kbase + bk8;

  f32x4 areg[4];
  bf16x8 breg[8];

  // prologue: prefetch iter 0
#pragma unroll
  for (int r = 0; r < 4; ++r) areg[r] = *(const f32x4*)(ap + (size_t)r * 16 * K_DIM);
#pragma unroll
  for (int c = 0; c < 8; ++c) breg[c] = *(const bf16x8*)(bp + (size_t)c * 32 * K_DIM);

  f32x4 acc[4][4];
  const f32x4 zero = {0.f, 0.f, 0.f, 0.f};
#pragma unroll
  for (int i = 0; i < 4; ++i)
#pragma unroll
    for (int j = 0; j < 4; ++j) acc[i][j] = zero;

  for (int it = 0; it < NITER; ++it) {
    __syncthreads();  // previous MFMA phase done reading LDS
    // ---- commit prefetched regs to LDS (compiler waits vmcnt here, per-wave) ----
#pragma unroll
    for (int r = 0; r < 4; ++r) {
      bf16x4 o = {(__bf16)areg[r][0], (__bf16)areg[r][1],
                  (__bf16)areg[r][2], (__bf16)areg[r][3]};
      *(bf16x4*)(&As[(arow + r * 16) * 72 + ac4 * 4]) = o;
    }
#pragma unroll
    for (int c = 0; c < 8; ++c)
      *(bf16x8*)(&Bs[(bn + c * 32) * 72 + bk8]) = breg[c];
    __syncthreads();  // LDS ready

    // ---- issue next iteration's global loads; they fly under the MFMAs ----
    if (it + 1 < NITER) {
      ap += BK;
      bp += BK;
#pragma unroll
      for (int r = 0; r < 4; ++r) areg[r] = *(const f32x4*)(ap + (size_t)r * 16 * K_DIM);
#pragma unroll
      for (int c = 0; c < 8; ++c) breg[c] = *(const bf16x8*)(bp + (size_t)c * 32 * K_DIM);
    }

    // ---- 32 MFMAs per wave ----
#pragma unroll
    for (int ks = 0; ks < 2; ++ks) {
      const int kb = ks * 32 + q * 8;
      bf16x8 a[4], b[4];
#pragma unroll
      for (int i = 0; i < 4; ++i)
        a[i] = *(const bf16x8*)(&As[(i * 16 + la) * 72 + kb]);
#pragma unroll
      for (int j = 0; j < 4; ++j)
        b[j] = *(const bf16x8*)(&Bs[(w * 64 + j * 16 + la) * 72 + kb]);
#pragma unroll
      for (int i = 0; i < 4; ++i)
#pragma unroll
        for (int j = 0; j < 4; ++j)
          acc[i][j] = __builtin_amdgcn_mfma_f32_16x16x32_bf16(a[i], b[j], acc[i][j], 0, 0, 0);
    }
  }

  // ---- epilogue: bf16 partials (C/D layout: col=lane&15, row=quad*4+reg) ----
  __bf16* pbase = part + (size_t)blockIdx.y * ((size_t)M_DIM * N_DIM);
#pragma unroll
  for (int i = 0; i < 4; ++i) {
    int r0 = m0 + i * 16 + q * 4;
#pragma unroll
    for (int j = 0; j < 4; ++j) {
      int c = w * 64 + j * 16 + la;
#pragma unroll
      for (int r = 0; r < 4; ++r)
        pbase[(size_t)(r0 + r) * N_DIM + c] = (__bf16)acc[i][j][r];
    }
  }
}

// ---------------- reduce partials + exact fp32 bit-flip correction + bias ----------------
__global__ __launch_bounds__(256) void reduce_kernel(const __bf16* __restrict__ part,
                                                     const float* __restrict__ x,
                                                     const float* __restrict__ W,
                                                     const float* __restrict__ bvec,
                                                     const float* __restrict__ coeffp,
                                                     const int* __restrict__ idx,
                                                     const int* __restrict__ bp,
                                                     float* __restrict__ out) {
  const int row = blockIdx.x;
  const int o = threadIdx.x;
  const int iv = idx[row];
  const float g = x[(size_t)row * K_DIM + iv];
  const int bits = __float_as_int(g) ^ (1 << bp[row]);
  const float upd = __int_as_float(bits) - g;  // swap_sim(g) - g, exact fp32
  const float coeff = coeffp[0];
  const size_t off = (size_t)row * N_DIM + o;
  float sum = 0.f;
#pragma unroll
  for (int s = 0; s < SPLIT; ++s)
    sum += (float)part[(size_t)s * ((size_t)M_DIM * N_DIM) + off];
  out[off] = sum + coeff * upd * W[(size_t)iv * N_DIM + o] + bvec[o];
}

extern "C" void kernel_launch(void* const* d_in, const int* in_sizes, int n_in,
                              void* d_out, int out_size, void* d_ws, size_t ws_size,
                              hipStream_t stream) {
  const float* x = (const float*)d_in[0];
  const float* W = (const float*)d_in[1];
  const float* b = (const float*)d_in[2];
  const float* coeff = (const float*)d_in[3];
  const int* idx = (const int*)d_in[4];
  const int* bp = (const int*)d_in[5];
  float* out = (float*)d_out;

  __bf16* Wt = (__bf16*)d_ws;
  const size_t wt_bytes = (size_t)K_DIM * N_DIM * 2;  // 8 MiB
  __bf16* part = (__bf16*)((char*)d_ws + wt_bytes);   // 8 x 2 MiB bf16 partials

  hipLaunchKernelGGL(wt_kernel, dim3(K_DIM / 64, N_DIM / 64), dim3(256), 0, stream, W, Wt);
  hipLaunchKernelGGL(gemm_kernel, dim3(M_DIM / 64, SPLIT), dim3(256), 0, stream,
                     x, Wt, part);
  hipLaunchKernelGGL(reduce_kernel, dim3(M_DIM), dim3(256), 0, stream,
                     part, x, W, b, coeff, idx, bp, out);
}